// Round 2
// baseline (2459.917 us; speedup 1.0000x reference)
//
#include <hip/hip_runtime.h>
#include <stdint.h>

// ---------------- problem constants ----------------
#define S_LEN   8192
#define DMODEL  3072
#define HDIM    768
#define NLM     32
#define MTOK    16384          // B*S token rows
#define MV      16448          // + 2*32 landmark rows (valid GEMM rows)
#define MP      16512          // padded (A/CTX allocation rows)
#define NQKV    9216
#define KDIM    3072
#define NKT     48             // K-tiles of 64
#define SCALE_F 0.036084391824351615f   // 1/sqrt(768)

// ---------------- workspace layout (bytes) ----------------
#define OFF_A    ((size_t)0)
#define OFF_WT   ((size_t)101449728)
#define OFF_QKV  ((size_t)176947200)
#define OFF_CTX  ((size_t)480116736)
#define OFF_BCAT ((size_t)581566464)
#define OFF_PART ((size_t)581615616)
#define OFF_ML   ((size_t)606781440)

#if defined(__has_builtin)
#if __has_builtin(__builtin_amdgcn_global_load_lds)
#define USE_GLL 1
#endif
#endif
#ifndef USE_GLL
#define USE_GLL 0
#endif

typedef __attribute__((ext_vector_type(8))) short bf8_t;             // 8 bf16 (4 VGPR) MFMA frag
typedef __attribute__((ext_vector_type(4))) float f4_t;
typedef __attribute__((ext_vector_type(4))) short s4_t;
typedef __attribute__((ext_vector_type(4))) unsigned short us4_t;

__device__ __forceinline__ float b2f(unsigned short u) {
  unsigned x = ((unsigned)u) << 16;
  float f;
  __builtin_memcpy(&f, &x, 4);
  return f;
}
__device__ __forceinline__ unsigned short f2b(float f) {  // RNE bf16
  unsigned x;
  __builtin_memcpy(&x, &f, 4);
  x += 0x7fffu + ((x >> 16) & 1u);
  return (unsigned short)(x >> 16);
}
__device__ __forceinline__ void load12(const unsigned short* p, float* f) {
  s4_t v0 = *(const s4_t*)p;
  s4_t v1 = *(const s4_t*)(p + 4);
  s4_t v2 = *(const s4_t*)(p + 8);
#pragma unroll
  for (int e = 0; e < 4; ++e) {
    f[e]     = b2f((unsigned short)v0[e]);
    f[4 + e] = b2f((unsigned short)v1[e]);
    f[8 + e] = b2f((unsigned short)v2[e]);
  }
}
__device__ __forceinline__ void store12(unsigned short* p, const float* f) {
  us4_t a = {f2b(f[0]), f2b(f[1]), f2b(f[2]), f2b(f[3])};
  us4_t b = {f2b(f[4]), f2b(f[5]), f2b(f[6]), f2b(f[7])};
  us4_t c = {f2b(f[8]), f2b(f[9]), f2b(f[10]), f2b(f[11])};
  *(us4_t*)p = a;
  *(us4_t*)(p + 4) = b;
  *(us4_t*)(p + 8) = c;
}

// ---------------- K: concatenated bias vector ----------------
__global__ __launch_bounds__(256) void build_bcat(const float* __restrict__ bq,
                                                  const float* __restrict__ bk,
                                                  const float* __restrict__ bv,
                                                  const float* __restrict__ bo,
                                                  float* __restrict__ bcat) {
  int n = blockIdx.x * 256 + threadIdx.x;            // 0..12287
  float v = (n < 3072) ? bq[n] : (n < 6144) ? bk[n - 3072]
          : (n < 9216) ? bv[n - 6144] : bo[n - 9216];
  bcat[n] = v;
}

// ---------------- K0: A matrix (tokens + landmark tokens), fp32 -> bf16 ----------------
__global__ __launch_bounds__(256) void build_a(const float* __restrict__ hs,
                                               const float* __restrict__ lemb,
                                               unsigned short* __restrict__ A) {
  size_t idx = (size_t)blockIdx.x * 256 + threadIdx.x;
  size_t e = idx * 4;
  int row = (int)(e / DMODEL);
  int col = (int)(e - (size_t)row * DMODEL);
  f4_t v;
  if (row < MTOK) {
    v = *(const f4_t*)(hs + e);
  } else if (row < MV) {
    int r2 = row - MTOK;
    int b = r2 >> 5, j = r2 & 31;
    int sel = (j * 511) / 31;          // matches linspace(0,511,32) truncation
    int li = sel * 16;
    f4_t a = *(const f4_t*)(hs + ((size_t)(b * S_LEN + li)) * DMODEL + col);
    f4_t c = *(const f4_t*)(lemb + (size_t)j * DMODEL + col);
    v = a + c;
  } else {
    v = (f4_t){0.f, 0.f, 0.f, 0.f};    // pad rows (stores masked later anyway)
  }
  us4_t o = {f2b(v[0]), f2b(v[1]), f2b(v[2]), f2b(v[3])};
  *(us4_t*)(A + e) = o;
}

// ---------------- K1: weight transpose, fp32 [K][N] -> bf16 [N][K] ----------------
__global__ __launch_bounds__(256) void wtrans(const float* __restrict__ W,
                                              unsigned short* __restrict__ Wt) {
  __shared__ float t[32][33];
  int n0 = blockIdx.x * 32, k0 = blockIdx.y * 32;
  int x = threadIdx.x, y = threadIdx.y;              // block (32,8)
#pragma unroll
  for (int i = 0; i < 4; ++i)
    t[y + i * 8][x] = W[(size_t)(k0 + y + i * 8) * DMODEL + n0 + x];
  __syncthreads();
#pragma unroll
  for (int i = 0; i < 4; ++i)
    Wt[(size_t)(n0 + y + i * 8) * DMODEL + k0 + x] = f2b(t[x][y + i * 8]);
}

// ---------------- K2: 256x256 8-phase bf16 MFMA GEMM  (m201-style template) ----------
// C[M][N] = A[M][K] * Bt[N][K]^T + bias.  512 threads = 8 waves (2M x 4N),
// BK=64 split into two K-halves; LDS 128 KiB = 2 dbuf x {A,B} x {KL,KH} 16 KiB
// sub-tiles.  T2 16B-slot XOR swizzle with f(row) = (row>>1)&3: within any 16
// consecutive lanes all 8 16B-positions of the 128B bank span are covered
// exactly twice (the r&3 variant covered only 4 -> residual 4-way conflict).
// Both-sides: pre-swizzled gll source + swizzled ds_read.  T4 counted vmcnt(6)
// once per K-tile.  T5 setprio.  T1 bijective XCD remap.
//
// LDS byte map (per region, 16 KiB): (kk-half)[row 0..255][slot 0..3]*16B,
//   slot s of row r holds global 16B chunk (s ^ ((r>>1)&3)) of that K-half.
// A region:  d*32768 + kk*16384 + row*64 + slot*16
// B region:  65536 + same.

#if USE_GLL
#define GLL16(SRC, OFF)                                                        \
  __builtin_amdgcn_global_load_lds(                                           \
      (const __attribute__((address_space(1))) void*)(SRC),                   \
      (__attribute__((address_space(3))) void*)(lds + (OFF)), 16, 0, 0)
#else
#define GLL16(SRC, OFF)                                                        \
  (*(bf8_t*)(lds + (OFF) + (unsigned)(threadIdx.x & 63) * 16) = *(const bf8_t*)(SRC))
#endif

// stage one K-half sub-tile (256 rows x 32 elems) = 2 x gll per thread
#define STG_A(TT, KH, DD)                                                      \
  do {                                                                         \
    const unsigned short* _s = gA0 + (size_t)(TT) * 64 + (KH) * 32;            \
    GLL16(_s, (unsigned)((DD) * 32768 + (KH) * 16384) + wl16);                 \
    GLL16(_s + (size_t)128 * KDIM,                                             \
          (unsigned)((DD) * 32768 + (KH) * 16384 + 8192) + wl16);              \
  } while (0)
#define STG_B(TT, KH, DD)                                                      \
  do {                                                                         \
    const unsigned short* _s = gB0 + (size_t)(TT) * 64 + (KH) * 32;            \
    GLL16(_s, (unsigned)(65536 + (DD) * 32768 + (KH) * 16384) + wl16);         \
    GLL16(_s + (size_t)128 * KDIM,                                             \
          (unsigned)(65536 + (DD) * 32768 + (KH) * 16384 + 8192) + wl16);      \
  } while (0)

#define LDA8(DD, KH, QM, MI)                                                   \
  (*(const bf8_t*)(lds + (DD) * 32768 + (KH) * 16384 + aBase + (QM) * 4096 +   \
                   (MI) * 1024))
#define LDB8(DD, KH, NI)                                                       \
  (*(const bf8_t*)(lds + (DD) * 32768 + (KH) * 16384 + bBase + (NI) * 1024))

#define MFMA16(Q)                                                              \
  do {                                                                         \
    __builtin_amdgcn_s_setprio(1);                                             \
    acc[(Q)+0][0] = __builtin_amdgcn_mfma_f32_16x16x32_bf16(a0, vb0, acc[(Q)+0][0], 0, 0, 0); \
    acc[(Q)+1][0] = __builtin_amdgcn_mfma_f32_16x16x32_bf16(a1, vb0, acc[(Q)+1][0], 0, 0, 0); \
    acc[(Q)+2][0] = __builtin_amdgcn_mfma_f32_16x16x32_bf16(a2, vb0, acc[(Q)+2][0], 0, 0, 0); \
    acc[(Q)+3][0] = __builtin_amdgcn_mfma_f32_16x16x32_bf16(a3, vb0, acc[(Q)+3][0], 0, 0, 0); \
    acc[(Q)+0][1] = __builtin_amdgcn_mfma_f32_16x16x32_bf16(a0, vb1, acc[(Q)+0][1], 0, 0, 0); \
    acc[(Q)+1][1] = __builtin_amdgcn_mfma_f32_16x16x32_bf16(a1, vb1, acc[(Q)+1][1], 0, 0, 0); \
    acc[(Q)+2][1] = __builtin_amdgcn_mfma_f32_16x16x32_bf16(a2, vb1, acc[(Q)+2][1], 0, 0, 0); \
    acc[(Q)+3][1] = __builtin_amdgcn_mfma_f32_16x16x32_bf16(a3, vb1, acc[(Q)+3][1], 0, 0, 0); \
    acc[(Q)+0][2] = __builtin_amdgcn_mfma_f32_16x16x32_bf16(a0, vb2, acc[(Q)+0][2], 0, 0, 0); \
    acc[(Q)+1][2] = __builtin_amdgcn_mfma_f32_16x16x32_bf16(a1, vb2, acc[(Q)+1][2], 0, 0, 0); \
    acc[(Q)+2][2] = __builtin_amdgcn_mfma_f32_16x16x32_bf16(a2, vb2, acc[(Q)+2][2], 0, 0, 0); \
    acc[(Q)+3][2] = __builtin_amdgcn_mfma_f32_16x16x32_bf16(a3, vb2, acc[(Q)+3][2], 0, 0, 0); \
    acc[(Q)+0][3] = __builtin_amdgcn_mfma_f32_16x16x32_bf16(a0, vb3, acc[(Q)+0][3], 0, 0, 0); \
    acc[(Q)+1][3] = __builtin_amdgcn_mfma_f32_16x16x32_bf16(a1, vb3, acc[(Q)+1][3], 0, 0, 0); \
    acc[(Q)+2][3] = __builtin_amdgcn_mfma_f32_16x16x32_bf16(a2, vb3, acc[(Q)+2][3], 0, 0, 0); \
    acc[(Q)+3][3] = __builtin_amdgcn_mfma_f32_16x16x32_bf16(a3, vb3, acc[(Q)+3][3], 0, 0, 0); \
    __builtin_amdgcn_s_setprio(0);                                             \
  } while (0)

__global__ __launch_bounds__(512, 2) void gemm256(const unsigned short* __restrict__ A,
                                                  const unsigned short* __restrict__ Bt,
                                                  const float* __restrict__ bias,
                                                  unsigned short* __restrict__ C,
                                                  int Mvalid, int N, int Ntiles) {
  extern __shared__ char lds[];
  const int tid = threadIdx.x;
  const int lane = tid & 63;
  const int wave = tid >> 6;
  const int WM = wave >> 2;                          // 0..1 (128-row half)
  const int WN = wave & 3;                           // 0..3 (64-col strip)
  const int row16 = lane & 15, quad = lane >> 4;

  // T1: bijective XCD-aware remap (m204)
  int nwg = (int)gridDim.x;
  int orig = (int)blockIdx.x;
  int q = nwg >> 3, r = nwg & 7;
  int xcd = orig & 7, lin = orig >> 3;
  int wg = (xcd < r ? xcd * (q + 1) : r * (q + 1) + (xcd - r) * q) + lin;
  const int tileM = (wg / Ntiles) * 256;
  const int tileN = (wg % Ntiles) * 256;

  // staging (write side): thread -> (row = tid>>2 [+128], slot = tid&3),
  // source chunk pre-swizzled so linear LDS dest ends up slot-swizzled.
  const int srow2 = tid >> 2;                        // 0..127
  const int scq = (tid & 3) ^ ((srow2 >> 1) & 3);    // f(row) = (row>>1)&3
  const unsigned short* gA0 = A + (size_t)(tileM + srow2) * KDIM + scq * 8;
  const unsigned short* gB0 = Bt + (size_t)(tileN + srow2) * KDIM + scq * 8;
  const unsigned wl16 = (unsigned)(tid & 448) * 16;  // wave-uniform LDS base part

  // read side: lane (row16, quad) reads slot (quad ^ ((row16>>1)&3)) -> chunk quad
  const unsigned co = (unsigned)((quad * 16) ^ (((row16 >> 1) & 3) << 4));
  const unsigned aBase = (unsigned)(WM * 8192 + row16 * 64) + co;
  const unsigned bBase = 65536u + (unsigned)(WN * 4096 + row16 * 64) + co;

  f4_t acc[8][4];
#pragma unroll
  for (int a = 0; a < 8; ++a)
#pragma unroll
    for (int b = 0; b < 4; ++b) acc[a][b] = (f4_t){0.f, 0.f, 0.f, 0.f};

  bf8_t vb0, vb1, vb2, vb3;

  // ---- prologue: issue order BKL0 AKL0 BKH0 AKH0 BKL1 AKL1 BKH1 (14 loads),
  //      wait to <=6 outstanding => K-tile 0 fully resident.
  STG_B(0, 0, 0); STG_A(0, 0, 0); STG_B(0, 1, 0); STG_A(0, 1, 0);
  STG_B(1, 0, 1); STG_A(1, 0, 1); STG_B(1, 1, 1);
  asm volatile("s_waitcnt vmcnt(6)" ::: "memory");
  __builtin_amdgcn_s_barrier();

  // ---- main loop: 4 phases per K-tile. Steady-state issue schedule:
  //  P0: AKH(t+1)->d^1   P1: BKL(t+2)->d   P2: AKL(t+2)->d   P3: BKH(t+2)->d
  //  vmcnt(6) at P3 completes everything through AKH(t+1) = next K-tile ready.
#pragma unroll 2
  for (int t = 0; t < NKT; ++t) {
    const int d = t & 1;
    {  // P0: kk=0, qm=0 (mi 0..3)
      bf8_t a0 = LDA8(d, 0, 0, 0), a1 = LDA8(d, 0, 0, 1),
            a2 = LDA8(d, 0, 0, 2), a3 = LDA8(d, 0, 0, 3);
      vb0 = LDB8(d, 0, 0); vb1 = LDB8(d, 0, 1);
      vb2 = LDB8(d, 0, 2); vb3 = LDB8(d, 0, 3);
      if (t + 1 < NKT) STG_A(t + 1, 1, d ^ 1);
      __builtin_amdgcn_s_barrier();
      asm volatile("s_waitcnt lgkmcnt(0)");
      MFMA16(0);
      __builtin_amdgcn_s_barrier();
    }
    {  // P1: kk=0, qm=1 (mi 4..7), reuses vb
      bf8_t a0 = LDA8(d, 0, 1, 0), a1 = LDA8(d, 0, 1, 1),
            a2 = LDA8(d, 0, 1, 2), a3 = LDA8(d, 0, 1, 3);
      if (t + 2 < NKT) STG_B(t + 2, 0, d);
      __builtin_amdgcn_s_barrier();
      asm volatile("s_waitcnt lgkmcnt(0)");
      MFMA16(4);
      __builtin_amdgcn_s_barrier();
    }
    {  // P2: kk=1, qm=0
      bf8_t a0 = LDA8(d, 1, 0, 0), a1 = LDA8(d, 1, 0, 1),
            a2 = LDA8(d, 1, 0, 2), a3 = LDA8(d, 1, 0, 3);
      vb0 = LDB8(d, 1, 0); vb1 = LDB8(d, 1, 1);
      vb2 = LDB8(d, 1, 2); vb3 = LDB8(d, 1, 3);
      if (t + 2 < NKT) STG_A(t + 2, 0, d);
      __builtin_amdgcn_s_barrier();
      asm volatile("s_waitcnt lgkmcnt(0)");
      MFMA16(0);
      __builtin_amdgcn_s_barrier();
    }
    {  // P3: kk=1, qm=1 ; counted vmcnt (never 0 in steady state)
      bf8_t a0 = LDA8(d, 1, 1, 0), a1 = LDA8(d, 1, 1, 1),
            a2 = LDA8(d, 1, 1, 2), a3 = LDA8(d, 1, 1, 3);
      if (t + 2 < NKT) STG_B(t + 2, 1, d);
      __builtin_amdgcn_s_barrier();
      asm volatile("s_waitcnt lgkmcnt(0)");
      MFMA16(4);
      if (t + 2 < NKT) asm volatile("s_waitcnt vmcnt(6)" ::: "memory");
      else             asm volatile("s_waitcnt vmcnt(0)" ::: "memory");
      __builtin_amdgcn_s_barrier();
    }
  }

  // ---- epilogue: D[m = WM*128+mi*16+quad*4+i][n = WN*64+ni*16+row16]
  float bv_[4];
#pragma unroll
  for (int ni = 0; ni < 4; ++ni) bv_[ni] = bias[tileN + WN * 64 + ni * 16 + row16];
#pragma unroll
  for (int mi = 0; mi < 8; ++mi) {
#pragma unroll
    for (int i = 0; i < 4; ++i) {
      int grow = tileM + WM * 128 + mi * 16 + quad * 4 + i;
      if (grow < Mvalid) {
        size_t base = (size_t)grow * N + tileN + WN * 64 + row16;
#pragma unroll
        for (int ni = 0; ni < 4; ++ni)
          C[base + ni * 16] = f2b(acc[mi][ni][i] + bv_[ni]);
      }
    }
  }
}

// ---------------- K3: global attention (every token over 32 landmarks), wave per (r,h) ----------------
__global__ __launch_bounds__(256) void glob_attn(const unsigned short* __restrict__ QKV,
                                                 unsigned short* __restrict__ CTX) {
  int wid = blockIdx.x * 4 + (threadIdx.x >> 6);     // 0..65535
  int lane = threadIdx.x & 63;
  int rr = wid & (S_LEN - 1);
  int bh = wid >> 13;
  int b = bh >> 2, h = bh & 3;
  size_t qrow = (size_t)(b * S_LEN + rr);

  float q[12];
  load12(QKV + qrow * NQKV + h * HDIM + lane * 12, q);

  const unsigned short* Kb = QKV + (size_t)(MTOK + b * NLM) * NQKV + DMODEL + h * HDIM + lane * 12;
  float sloc = 0.f;
  for (int j = 0; j < NLM; ++j) {
    float kv[12];
    load12(Kb + (size_t)j * NQKV, kv);
    float p = 0.f;
#pragma unroll
    for (int e = 0; e < 12; ++e) p += q[e] * kv[e];
#pragma unroll
    for (int off = 32; off; off >>= 1) p += __shfl_xor(p, off);
    if ((lane & 31) == j) sloc = p * SCALE_F;
  }
  float m = sloc;
#pragma unroll
  for (int off = 16; off; off >>= 1) m = fmaxf(m, __shfl_xor(m, off));
  float p = __expf(sloc - m);
  float l = p;
#pragma unroll
  for (int off = 16; off; off >>= 1) l += __shfl_xor(l, off);
  float w = p / l;

  float ctx[12];
#pragma unroll
  for (int e = 0; e < 12; ++e) ctx[e] = 0.f;
  const unsigned short* Vb = QKV + (size_t)(MTOK + b * NLM) * NQKV + 2 * DMODEL + h * HDIM + lane * 12;
  for (int j = 0; j < NLM; ++j) {
    float wj = __shfl(w, j);
    float vv[12];
    load12(Vb + (size_t)j * NQKV, vv);
#pragma unroll
    for (int e = 0; e < 12; ++e) ctx[e] += wj * vv[e];
  }
  store12(CTX + qrow * DMODEL + h * HDIM + lane * 12, ctx);
}

// ---------------- K4: landmark attention partials, JG=8 landmarks per wave ----------------
// Each wave owns (b, h, jg, kc): 8 landmarks x one 256-row K/V chunk.
// K/V rows are loaded ONCE per 8 landmarks (was: once per landmark) ->
// effective K/V traffic 6.4 GB -> 0.8 GB.  Per-(j,kc) accumulation order is
// bitwise identical to the old kernel; partial layout unchanged (lm_combine
// untouched).  1024 waves -> 256 blocks (1/CU, 1 wave/SIMD) ->
// launch_bounds(256,1) so ~250 VGPRs fit without spill.
__global__ __launch_bounds__(256, 1) void lm_attn_part(const unsigned short* __restrict__ QKV,
                                                       float* __restrict__ ctxpart,
                                                       float* __restrict__ mlpart) {
  int wid = blockIdx.x * 4 + (threadIdx.x >> 6);     // 0..1023
  int lane = threadIdx.x & 63;
  int kc = wid & 31, jg = (wid >> 5) & 3, h = (wid >> 7) & 3, b = wid >> 9;

  float qreg[8][12];
#pragma unroll
  for (int jj = 0; jj < 8; ++jj)
    load12(QKV + (size_t)(MTOK + b * NLM + jg * 8 + jj) * NQKV + h * HDIM + lane * 12,
           qreg[jj]);

  float m[8], l[8], ctx[8][12];
#pragma unroll
  for (int jj = 0; jj < 8; ++jj) {
    m[jj] = -1e30f;
    l[jj] = 0.f;
#pragma unroll
    for (int e = 0; e < 12; ++e) ctx[jj][e] = 0.f;
  }

  for (int k = kc * 256; k < kc * 256 + 256; ++k) {
    size_t row = (size_t)(b * S_LEN + k);
    float kv[12], vv[12];
    load12(QKV + row * NQKV + DMODEL + h * HDIM + lane * 12, kv);
    float s[8];
#pragma unroll
    for (int jj = 0; jj < 8; ++jj) {
      float p = 0.f;
#pragma unroll
      for (int e = 0; e < 12; ++e) p += qreg[jj][e] * kv[e];
      s[jj] = p;
    }
#pragma unroll
    for (int jj = 0; jj < 8; ++jj) {
#pragma unroll
      for (int off = 32; off; off >>= 1) s[jj] += __shfl_xor(s[jj], off);
      s[jj] *= SCALE_F;
    }
    load12(QKV + row * NQKV + 2 * DMODEL + h * HDIM + lane * 12, vv);
#pragma unroll
    for (int jj = 0; jj < 8; ++jj) {
      if (s[jj] <= m[jj]) {                          // wave-uniform branch
        float pp = __expf(s[jj] - m[jj]);
        l[jj] += pp;
#pragma unroll
        for (int e = 0; e < 12; ++e) ctx[jj][e] += pp * vv[e];
      } else {
        float al = __expf(m[jj] - s[jj]);
        m[jj] = s[jj];
        l[jj] = l[jj] * al + 1.f;
#pragma unroll
        for (int e = 0; e < 12; ++e) ctx[jj][e] = ctx[jj][e] * al + vv[e];
      }
    }
  }

#pragma unroll
  for (int jj = 0; jj < 8; ++jj) {
    int wid_old = (((b * 4 + h) * 32) + (jg * 8 + jj)) * 32 + kc;
    float* cp = ctxpart + (size_t)wid_old * HDIM + lane * 12;
#pragma unroll
    for (int e = 0; e < 12; ++e) cp[e] = ctx[jj][e];
    if (lane == 0) {
      mlpart[wid_old * 2] = m[jj];
      mlpart[wid_old * 2 + 1] = l[jj];
    }
  }
}

// ---------------- K4b: merge landmark partials, wave per (b,h,j) ----------------
__global__ __launch_bounds__(256) void lm_combine(const float* __restrict__ ctxpart,
                                                  const float* __restrict__ mlpart,
                                                  unsigned short* __restrict__ CTX) {
  int wid = blockIdx.x * 4 + (threadIdx.x >> 6);     // 0..255
  int lane = threadIdx.x & 63;
  int j = wid & 31, h = (wid >> 5) & 3, b = wid >> 7;
  int base = wid * 32;
  int kcl = lane & 31;
  float mk = mlpart[(base + kcl) * 2];
  float lk = mlpart[(base + kcl) * 2 + 1];
  float mm = mk;
#pragma unroll
  for (int off = 16; off; off >>= 1) mm = fmaxf(mm, __shfl_xor(mm, off));
  float al = __expf(mk - mm);
  float ls = al * lk;
#pragma unroll
  for (int off = 16; off; off >>= 1) ls += __shfl_xor(ls, off);

  float ctx[12];
#pragma unroll
  for (int e = 0; e < 12; ++e) ctx[e] = 0.f;
  for (int kc = 0; kc < 32; ++kc) {
    float a = __shfl(al, kc);
    const float* cp = ctxpart + (size_t)(base + kc) * HDIM + lane * 12;
#pragma unroll
    for (int e = 0; e < 12; ++e) ctx[e] += a * cp[e];
  }
  float inv = 1.f / ls;
#pragma unroll
  for (int e = 0; e < 12; ++e) ctx[e] *= inv;
  store12(CTX + (size_t)(MTOK + b * NLM + j) * DMODEL + h * HDIM + lane * 12, ctx);
}

// ---------------- K6: out = (landmark? lm_proj : hs) + global_proj ----------------
__global__ __launch_bounds__(256) void compose(const float* __restrict__ hs,
                                               const unsigned short* __restrict__ PROJ,
                                               float* __restrict__ out) {
  size_t idx = (size_t)blockIdx.x * 256 + threadIdx.x;
  size_t e = idx * 4;
  int row = (int)(e / DMODEL);
  int col = (int)(e - (size_t)row * DMODEL);
  int b = row >> 13, s = row & (S_LEN - 1);

  us4_t g4 = *(const us4_t*)(PROJ + (size_t)row * DMODEL + col);
  int j = -1;
  if ((s & 15) == 0) {
    int sel = s >> 4;
    int jc = (sel * 31 + 510) / 511;                 // ceil(sel*31/511): unique candidate
    if (jc < 32 && (jc * 511) / 31 == sel) j = jc;
  }
  f4_t base;
  if (j >= 0) {
    us4_t l4 = *(const us4_t*)(PROJ + (size_t)(MTOK + b * NLM + j) * DMODEL + col);
    base = (f4_t){b2f(l4[0]), b2f(l4[1]), b2f(l4[2]), b2f(l4[3])};
  } else {
    base = *(const f4_t*)(hs + e);
  }
  f4_t o = {base[0] + b2f(g4[0]), base[1] + b2f(g4[1]),
            base[2] + b2f(g4[2]), base[3] + b2f(g4[3])};
  *(f4_t*)(out + e) = o;
}

// ---------------- launch ----------------
extern "C" void kernel_launch(void* const* d_in, const int* in_sizes, int n_in,
                              void* d_out, int out_size, void* d_ws, size_t ws_size,
                              hipStream_t stream) {
  const float* hs   = (const float*)d_in[0];
  const float* lemb = (const float*)d_in[1];
  const float* Wq   = (const float*)d_in[2];
  const float* bq   = (const float*)d_in[3];
  const float* Wk   = (const float*)d_in[4];
  const float* bk   = (const float*)d_in[5];
  const float* Wv   = (const float*)d_in[6];
  const float* bv   = (const float*)d_in[7];
  const float* Wo   = (const float*)d_in[8];
  const float* bo   = (const float*)d_in[9];
  float* out = (float*)d_out;
  char* ws = (char*)d_ws;

  unsigned short* A    = (unsigned short*)(ws + OFF_A);
  unsigned short* Wt   = (unsigned short*)(ws + OFF_WT);
  unsigned short* QKV  = (unsigned short*)(ws + OFF_QKV);
  unsigned short* CTX  = (unsigned short*)(ws + OFF_CTX);
  float*          bcat = (float*)(ws + OFF_BCAT);
  float*          part = (float*)(ws + OFF_PART);
  float*          ml   = (float*)(ws + OFF_ML);
  unsigned short* PROJ = (unsigned short*)(ws + OFF_A);  // A dead after GEMM1; reuse

  static bool attr_set = false;
  if (!attr_set) {
    (void)hipFuncSetAttribute(reinterpret_cast<const void*>(gemm256),
                              hipFuncAttributeMaxDynamicSharedMemorySize, 131072);
    attr_set = true;
  }

  build_bcat<<<dim3(48), dim3(256), 0, stream>>>(bq, bk, bv, bo, bcat);
  build_a<<<dim3(49536), dim3(256), 0, stream>>>(hs, lemb, A);
  wtrans<<<dim3(96, 96), dim3(32, 8), 0, stream>>>(Wq, Wt);
  wtrans<<<dim3(96, 96), dim3(32, 8), 0, stream>>>(Wk, Wt + (size_t)3072 * KDIM);
  wtrans<<<dim3(96, 96), dim3(32, 8), 0, stream>>>(Wv, Wt + (size_t)6144 * KDIM);
  wtrans<<<dim3(96, 96), dim3(32, 8), 0, stream>>>(Wo, Wt + (size_t)9216 * KDIM);

  // QKV for tokens + landmarks in one GEMM: [16448, 9216]; 65 x 36 tiles of 256
  gemm256<<<dim3(65 * 36), dim3(512), 131072, stream>>>(A, Wt, bcat, QKV, MV, NQKV, 36);

  glob_attn<<<dim3(16384), dim3(256), 0, stream>>>(QKV, CTX);
  lm_attn_part<<<dim3(256), dim3(256), 0, stream>>>(QKV, part, ml);
  lm_combine<<<dim3(64), dim3(256), 0, stream>>>(part, ml, CTX);

  // output projection for both ctx sets: [16448, 3072]; 65 x 12 tiles of 256
  gemm256<<<dim3(65 * 12), dim3(512), 131072, stream>>>(
      CTX, Wt + (size_t)9216 * KDIM, bcat + 9216, PROJ, MV, DMODEL, 12);

  compose<<<dim3(49152), dim3(256), 0, stream>>>(hs, PROJ, out);
}

// Round 3
// 2019.455 us; speedup vs baseline: 1.2181x; 1.2181x over previous
//
#include <hip/hip_runtime.h>
#include <stdint.h>

// ---------------- problem constants ----------------
#define S_LEN   8192
#define DMODEL  3072
#define HDIM    768
#define NLM     32
#define MTOK    16384          // B*S token rows
#define MV      16448          // + 2*32 landmark rows (valid GEMM rows)
#define MP      16512          // padded (A/CTX allocation rows)
#define NQKV    9216
#define KDIM    3072
#define NKT     48             // K-tiles of 64
#define SCALE_F 0.036084391824351615f   // 1/sqrt(768)

// ---------------- workspace layout (bytes) ----------------
// A        bf16 [MP][3072]   dead after GEMM1. Reused: lm ctx partials (50 MB,
//                            consumed by lm_combine) THEN PROJ (GEMM2 output).
// Wt       bf16 [12288][3072]
// QKV      bf16 [MV][9216]
// CTX      bf16 [MP][3072]
// bcat     f32  [12288]
// PART region reused: KT (393KB) | VT (393KB) | ml (131KB)
#define OFF_A    ((size_t)0)
#define OFF_WT   ((size_t)101449728)
#define OFF_QKV  ((size_t)176947200)
#define OFF_CTX  ((size_t)480116736)
#define OFF_BCAT ((size_t)581566464)
#define OFF_PART ((size_t)581615616)
#define OFF_KT   (OFF_PART)
#define OFF_VT   (OFF_PART + 393216)
#define OFF_ML2  (OFF_PART + 786432)
#define OFF_CP   (OFF_A)               // lm ctx partials: 16384 x 768 f32 = 50.3 MB

#if defined(__has_builtin)
#if __has_builtin(__builtin_amdgcn_global_load_lds)
#define USE_GLL 1
#endif
#endif
#ifndef USE_GLL
#define USE_GLL 0
#endif

typedef __attribute__((ext_vector_type(8))) short bf8_t;             // 8 bf16 (4 VGPR) MFMA frag
typedef __attribute__((ext_vector_type(4))) float f4_t;
typedef __attribute__((ext_vector_type(4))) short s4_t;
typedef __attribute__((ext_vector_type(4))) unsigned short us4_t;

__device__ __forceinline__ float b2f(unsigned short u) {
  unsigned x = ((unsigned)u) << 16;
  float f;
  __builtin_memcpy(&f, &x, 4);
  return f;
}
__device__ __forceinline__ unsigned short f2b(float f) {  // RNE bf16
  unsigned x;
  __builtin_memcpy(&x, &f, 4);
  x += 0x7fffu + ((x >> 16) & 1u);
  return (unsigned short)(x >> 16);
}
__device__ __forceinline__ void load12(const unsigned short* p, float* f) {
  s4_t v0 = *(const s4_t*)p;
  s4_t v1 = *(const s4_t*)(p + 4);
  s4_t v2 = *(const s4_t*)(p + 8);
#pragma unroll
  for (int e = 0; e < 4; ++e) {
    f[e]     = b2f((unsigned short)v0[e]);
    f[4 + e] = b2f((unsigned short)v1[e]);
    f[8 + e] = b2f((unsigned short)v2[e]);
  }
}
__device__ __forceinline__ void store12(unsigned short* p, const float* f) {
  us4_t a = {f2b(f[0]), f2b(f[1]), f2b(f[2]), f2b(f[3])};
  us4_t b = {f2b(f[4]), f2b(f[5]), f2b(f[6]), f2b(f[7])};
  us4_t c = {f2b(f[8]), f2b(f[9]), f2b(f[10]), f2b(f[11])};
  *(us4_t*)p = a;
  *(us4_t*)(p + 4) = b;
  *(us4_t*)(p + 8) = c;
}

// ---------------- K: concatenated bias vector ----------------
__global__ __launch_bounds__(256) void build_bcat(const float* __restrict__ bq,
                                                  const float* __restrict__ bk,
                                                  const float* __restrict__ bv,
                                                  const float* __restrict__ bo,
                                                  float* __restrict__ bcat) {
  int n = blockIdx.x * 256 + threadIdx.x;            // 0..12287
  float v = (n < 3072) ? bq[n] : (n < 6144) ? bk[n - 3072]
          : (n < 9216) ? bv[n - 6144] : bo[n - 9216];
  bcat[n] = v;
}

// ---------------- K0: A matrix (tokens + landmark tokens), fp32 -> bf16 ----------------
__global__ __launch_bounds__(256) void build_a(const float* __restrict__ hs,
                                               const float* __restrict__ lemb,
                                               unsigned short* __restrict__ A) {
  size_t idx = (size_t)blockIdx.x * 256 + threadIdx.x;
  size_t e = idx * 4;
  int row = (int)(e / DMODEL);
  int col = (int)(e - (size_t)row * DMODEL);
  f4_t v;
  if (row < MTOK) {
    v = *(const f4_t*)(hs + e);
  } else if (row < MV) {
    int r2 = row - MTOK;
    int b = r2 >> 5, j = r2 & 31;
    int sel = (j * 511) / 31;          // matches linspace(0,511,32) truncation
    int li = sel * 16;
    f4_t a = *(const f4_t*)(hs + ((size_t)(b * S_LEN + li)) * DMODEL + col);
    f4_t c = *(const f4_t*)(lemb + (size_t)j * DMODEL + col);
    v = a + c;
  } else {
    v = (f4_t){0.f, 0.f, 0.f, 0.f};    // pad rows (stores masked later anyway)
  }
  us4_t o = {f2b(v[0]), f2b(v[1]), f2b(v[2]), f2b(v[3])};
  *(us4_t*)(A + e) = o;
}

// ---------------- K1: weight transpose, fp32 [K][N] -> bf16 [N][K] ----------------
__global__ __launch_bounds__(256) void wtrans(const float* __restrict__ W,
                                              unsigned short* __restrict__ Wt) {
  __shared__ float t[32][33];
  int n0 = blockIdx.x * 32, k0 = blockIdx.y * 32;
  int x = threadIdx.x, y = threadIdx.y;              // block (32,8)
#pragma unroll
  for (int i = 0; i < 4; ++i)
    t[y + i * 8][x] = W[(size_t)(k0 + y + i * 8) * DMODEL + n0 + x];
  __syncthreads();
#pragma unroll
  for (int i = 0; i < 4; ++i)
    Wt[(size_t)(n0 + y + i * 8) * DMODEL + k0 + x] = f2b(t[x][y + i * 8]);
}

// ---------------- K2: 256x256 8-phase bf16 MFMA GEMM (verified: 0 bank conflicts) ----
#if USE_GLL
#define GLL16(SRC, OFF)                                                        \
  __builtin_amdgcn_global_load_lds(                                           \
      (const __attribute__((address_space(1))) void*)(SRC),                   \
      (__attribute__((address_space(3))) void*)(lds + (OFF)), 16, 0, 0)
#else
#define GLL16(SRC, OFF)                                                        \
  (*(bf8_t*)(lds + (OFF) + (unsigned)(threadIdx.x & 63) * 16) = *(const bf8_t*)(SRC))
#endif

#define STG_A(TT, KH, DD)                                                      \
  do {                                                                         \
    const unsigned short* _s = gA0 + (size_t)(TT) * 64 + (KH) * 32;            \
    GLL16(_s, (unsigned)((DD) * 32768 + (KH) * 16384) + wl16);                 \
    GLL16(_s + (size_t)128 * KDIM,                                             \
          (unsigned)((DD) * 32768 + (KH) * 16384 + 8192) + wl16);              \
  } while (0)
#define STG_B(TT, KH, DD)                                                      \
  do {                                                                         \
    const unsigned short* _s = gB0 + (size_t)(TT) * 64 + (KH) * 32;            \
    GLL16(_s, (unsigned)(65536 + (DD) * 32768 + (KH) * 16384) + wl16);         \
    GLL16(_s + (size_t)128 * KDIM,                                             \
          (unsigned)(65536 + (DD) * 32768 + (KH) * 16384 + 8192) + wl16);      \
  } while (0)

#define LDA8(DD, KH, QM, MI)                                                   \
  (*(const bf8_t*)(lds + (DD) * 32768 + (KH) * 16384 + aBase + (QM) * 4096 +   \
                   (MI) * 1024))
#define LDB8(DD, KH, NI)                                                       \
  (*(const bf8_t*)(lds + (DD) * 32768 + (KH) * 16384 + bBase + (NI) * 1024))

#define MFMA16(Q)                                                              \
  do {                                                                         \
    __builtin_amdgcn_s_setprio(1);                                             \
    acc[(Q)+0][0] = __builtin_amdgcn_mfma_f32_16x16x32_bf16(a0, vb0, acc[(Q)+0][0], 0, 0, 0); \
    acc[(Q)+1][0] = __builtin_amdgcn_mfma_f32_16x16x32_bf16(a1, vb0, acc[(Q)+1][0], 0, 0, 0); \
    acc[(Q)+2][0] = __builtin_amdgcn_mfma_f32_16x16x32_bf16(a2, vb0, acc[(Q)+2][0], 0, 0, 0); \
    acc[(Q)+3][0] = __builtin_amdgcn_mfma_f32_16x16x32_bf16(a3, vb0, acc[(Q)+3][0], 0, 0, 0); \
    acc[(Q)+0][1] = __builtin_amdgcn_mfma_f32_16x16x32_bf16(a0, vb1, acc[(Q)+0][1], 0, 0, 0); \
    acc[(Q)+1][1] = __builtin_amdgcn_mfma_f32_16x16x32_bf16(a1, vb1, acc[(Q)+1][1], 0, 0, 0); \
    acc[(Q)+2][1] = __builtin_amdgcn_mfma_f32_16x16x32_bf16(a2, vb1, acc[(Q)+2][1], 0, 0, 0); \
    acc[(Q)+3][1] = __builtin_amdgcn_mfma_f32_16x16x32_bf16(a3, vb1, acc[(Q)+3][1], 0, 0, 0); \
    acc[(Q)+0][2] = __builtin_amdgcn_mfma_f32_16x16x32_bf16(a0, vb2, acc[(Q)+0][2], 0, 0, 0); \
    acc[(Q)+1][2] = __builtin_amdgcn_mfma_f32_16x16x32_bf16(a1, vb2, acc[(Q)+1][2], 0, 0, 0); \
    acc[(Q)+2][2] = __builtin_amdgcn_mfma_f32_16x16x32_bf16(a2, vb2, acc[(Q)+2][2], 0, 0, 0); \
    acc[(Q)+3][2] = __builtin_amdgcn_mfma_f32_16x16x32_bf16(a3, vb2, acc[(Q)+3][2], 0, 0, 0); \
    acc[(Q)+0][3] = __builtin_amdgcn_mfma_f32_16x16x32_bf16(a0, vb3, acc[(Q)+0][3], 0, 0, 0); \
    acc[(Q)+1][3] = __builtin_amdgcn_mfma_f32_16x16x32_bf16(a1, vb3, acc[(Q)+1][3], 0, 0, 0); \
    acc[(Q)+2][3] = __builtin_amdgcn_mfma_f32_16x16x32_bf16(a2, vb3, acc[(Q)+2][3], 0, 0, 0); \
    acc[(Q)+3][3] = __builtin_amdgcn_mfma_f32_16x16x32_bf16(a3, vb3, acc[(Q)+3][3], 0, 0, 0); \
    __builtin_amdgcn_s_setprio(0);                                             \
  } while (0)

__global__ __launch_bounds__(512, 2) void gemm256(const unsigned short* __restrict__ A,
                                                  const unsigned short* __restrict__ Bt,
                                                  const float* __restrict__ bias,
                                                  unsigned short* __restrict__ C,
                                                  int Mvalid, int N, int Ntiles) {
  extern __shared__ char lds[];
  const int tid = threadIdx.x;
  const int lane = tid & 63;
  const int wave = tid >> 6;
  const int WM = wave >> 2;                          // 0..1 (128-row half)
  const int WN = wave & 3;                           // 0..3 (64-col strip)
  const int row16 = lane & 15, quad = lane >> 4;

  // T1: bijective XCD-aware remap (m204)
  int nwg = (int)gridDim.x;
  int orig = (int)blockIdx.x;
  int q = nwg >> 3, r = nwg & 7;
  int xcd = orig & 7, lin = orig >> 3;
  int wg = (xcd < r ? xcd * (q + 1) : r * (q + 1) + (xcd - r) * q) + lin;
  const int tileM = (wg / Ntiles) * 256;
  const int tileN = (wg % Ntiles) * 256;

  const int srow2 = tid >> 2;                        // 0..127
  const int scq = (tid & 3) ^ ((srow2 >> 1) & 3);    // f(row) = (row>>1)&3
  const unsigned short* gA0 = A + (size_t)(tileM + srow2) * KDIM + scq * 8;
  const unsigned short* gB0 = Bt + (size_t)(tileN + srow2) * KDIM + scq * 8;
  const unsigned wl16 = (unsigned)(tid & 448) * 16;  // wave-uniform LDS base part

  const unsigned co = (unsigned)((quad * 16) ^ (((row16 >> 1) & 3) << 4));
  const unsigned aBase = (unsigned)(WM * 8192 + row16 * 64) + co;
  const unsigned bBase = 65536u + (unsigned)(WN * 4096 + row16 * 64) + co;

  f4_t acc[8][4];
#pragma unroll
  for (int a = 0; a < 8; ++a)
#pragma unroll
    for (int b = 0; b < 4; ++b) acc[a][b] = (f4_t){0.f, 0.f, 0.f, 0.f};

  bf8_t vb0, vb1, vb2, vb3;

  STG_B(0, 0, 0); STG_A(0, 0, 0); STG_B(0, 1, 0); STG_A(0, 1, 0);
  STG_B(1, 0, 1); STG_A(1, 0, 1); STG_B(1, 1, 1);
  asm volatile("s_waitcnt vmcnt(6)" ::: "memory");
  __builtin_amdgcn_s_barrier();

#pragma unroll 2
  for (int t = 0; t < NKT; ++t) {
    const int d = t & 1;
    {  // P0: kk=0, qm=0 (mi 0..3)
      bf8_t a0 = LDA8(d, 0, 0, 0), a1 = LDA8(d, 0, 0, 1),
            a2 = LDA8(d, 0, 0, 2), a3 = LDA8(d, 0, 0, 3);
      vb0 = LDB8(d, 0, 0); vb1 = LDB8(d, 0, 1);
      vb2 = LDB8(d, 0, 2); vb3 = LDB8(d, 0, 3);
      if (t + 1 < NKT) STG_A(t + 1, 1, d ^ 1);
      __builtin_amdgcn_s_barrier();
      asm volatile("s_waitcnt lgkmcnt(0)");
      MFMA16(0);
      __builtin_amdgcn_s_barrier();
    }
    {  // P1: kk=0, qm=1 (mi 4..7), reuses vb
      bf8_t a0 = LDA8(d, 0, 1, 0), a1 = LDA8(d, 0, 1, 1),
            a2 = LDA8(d, 0, 1, 2), a3 = LDA8(d, 0, 1, 3);
      if (t + 2 < NKT) STG_B(t + 2, 0, d);
      __builtin_amdgcn_s_barrier();
      asm volatile("s_waitcnt lgkmcnt(0)");
      MFMA16(4);
      __builtin_amdgcn_s_barrier();
    }
    {  // P2: kk=1, qm=0
      bf8_t a0 = LDA8(d, 1, 0, 0), a1 = LDA8(d, 1, 0, 1),
            a2 = LDA8(d, 1, 0, 2), a3 = LDA8(d, 1, 0, 3);
      vb0 = LDB8(d, 1, 0); vb1 = LDB8(d, 1, 1);
      vb2 = LDB8(d, 1, 2); vb3 = LDB8(d, 1, 3);
      if (t + 2 < NKT) STG_A(t + 2, 0, d);
      __builtin_amdgcn_s_barrier();
      asm volatile("s_waitcnt lgkmcnt(0)");
      MFMA16(0);
      __builtin_amdgcn_s_barrier();
    }
    {  // P3: kk=1, qm=1 ; counted vmcnt (never 0 in steady state)
      bf8_t a0 = LDA8(d, 1, 1, 0), a1 = LDA8(d, 1, 1, 1),
            a2 = LDA8(d, 1, 1, 2), a3 = LDA8(d, 1, 1, 3);
      if (t + 2 < NKT) STG_B(t + 2, 1, d);
      __builtin_amdgcn_s_barrier();
      asm volatile("s_waitcnt lgkmcnt(0)");
      MFMA16(4);
      if (t + 2 < NKT) asm volatile("s_waitcnt vmcnt(6)" ::: "memory");
      else             asm volatile("s_waitcnt vmcnt(0)" ::: "memory");
      __builtin_amdgcn_s_barrier();
    }
  }

  float bv_[4];
#pragma unroll
  for (int ni = 0; ni < 4; ++ni) bv_[ni] = bias[tileN + WN * 64 + ni * 16 + row16];
#pragma unroll
  for (int mi = 0; mi < 8; ++mi) {
#pragma unroll
    for (int i = 0; i < 4; ++i) {
      int grow = tileM + WM * 128 + mi * 16 + quad * 4 + i;
      if (grow < Mvalid) {
        size_t base = (size_t)grow * N + tileN + WN * 64 + row16;
#pragma unroll
        for (int ni = 0; ni < 4; ++ni)
          C[base + ni * 16] = f2b(acc[mi][ni][i] + bv_[ni]);
      }
    }
  }
}

// ---------------- K2b: landmark K/V fragment prep ----------------
// KT[bh][c=0..95][j=0..31][8] = K[j][c*8+e]   (B-frag order for QK^T)
// VT[bh][d=0..767][j=0..31]   = V[j][d]       (B-frag order for PV)
__global__ __launch_bounds__(256) void kv_prep(const unsigned short* __restrict__ QKV,
                                               unsigned short* __restrict__ KT,
                                               unsigned short* __restrict__ VT) {
  int idx = blockIdx.x * 256 + threadIdx.x;          // 0..49151
  if (idx < 24576) {                                 // KT: 8 bh x 3072 chunks
    int bh = idx / 3072, i = idx % 3072;
    int b = bh >> 2, h = bh & 3;
    int j = i & 31, c = i >> 5;
    bf8_t v = *(const bf8_t*)(QKV + (size_t)(MTOK + b * NLM + j) * NQKV + DMODEL +
                              h * HDIM + c * 8);
    *(bf8_t*)(KT + (size_t)bh * 24576 + (size_t)(c * 32 + j) * 8) = v;
  } else {                                           // VT: 8 bh x 768 d x 4 slots
    int i2 = idx - 24576;
    int bh = i2 / 3072, r = i2 % 3072;
    int b = bh >> 2, h = bh & 3;
    int d = r >> 2, slot = r & 3;
    unsigned short vals[8];
#pragma unroll
    for (int e = 0; e < 8; ++e)
      vals[e] = QKV[(size_t)(MTOK + b * NLM + slot * 8 + e) * NQKV + 2 * DMODEL +
                    h * HDIM + d];
    unsigned short* p = VT + (size_t)bh * 24576 + (size_t)d * 32 + slot * 8;
    *(us4_t*)p = (us4_t){vals[0], vals[1], vals[2], vals[3]};
    *(us4_t*)(p + 4) = (us4_t){vals[4], vals[5], vals[6], vals[7]};
  }
}

// ---------------- K3: global attention via MFMA ----------------
// Block = 4 waves x 32 q-rows = 128 rows; grid = 2b x 4h x 64 qtiles = 512.
// Per wave: QK^T (2m x 2n x 24k = 96 MFMA) -> softmax (8 rows/lane, 16-lane
// shfl reduce) -> P bf16 in LDS (2KB/wave) -> PV (2m x 4n x 12 dchunks = 96
// MFMA, V-frags from L2-resident VT).  Fragment layouts mirror gemm256:
// A/B operand: lane holds [idx=lane&15][k=(lane>>4)*8+e]; D: row=quad*4+reg,
// col=lane&15.
__global__ __launch_bounds__(256, 2) void glob_attn(const unsigned short* __restrict__ QKV,
                                                    const unsigned short* __restrict__ KT,
                                                    const unsigned short* __restrict__ VT,
                                                    unsigned short* __restrict__ CTX) {
  __shared__ unsigned short P_s[4][32][32];          // [wave][row][landmark]
  const int tid = threadIdx.x;
  const int lane = tid & 63;
  const int w = tid >> 6;
  const int row16 = lane & 15, quad = lane >> 4;

  const int qt = blockIdx.x & 63;
  const int h = (blockIdx.x >> 6) & 3;
  const int b = blockIdx.x >> 8;
  const int bh = b * 4 + h;
  const int rowbase = b * S_LEN + qt * 128 + w * 32; // this wave's 32 q-rows

  const unsigned short* KTb = KT + (size_t)bh * 24576;
  const unsigned short* VTb = VT + (size_t)bh * 24576;

  // ---- QK^T ----
  f4_t sc[2][2];
#pragma unroll
  for (int mi = 0; mi < 2; ++mi)
#pragma unroll
    for (int ni = 0; ni < 2; ++ni) sc[mi][ni] = (f4_t){0.f, 0.f, 0.f, 0.f};

#pragma unroll
  for (int kt = 0; kt < 24; ++kt) {
    bf8_t kb0 = *(const bf8_t*)(KTb + (size_t)((kt * 4 + quad) * 32 + row16) * 8);
    bf8_t kb1 = *(const bf8_t*)(KTb + (size_t)((kt * 4 + quad) * 32 + 16 + row16) * 8);
    bf8_t qa0 = *(const bf8_t*)(QKV + (size_t)(rowbase + row16) * NQKV + h * HDIM +
                                kt * 32 + quad * 8);
    bf8_t qa1 = *(const bf8_t*)(QKV + (size_t)(rowbase + 16 + row16) * NQKV + h * HDIM +
                                kt * 32 + quad * 8);
    sc[0][0] = __builtin_amdgcn_mfma_f32_16x16x32_bf16(qa0, kb0, sc[0][0], 0, 0, 0);
    sc[0][1] = __builtin_amdgcn_mfma_f32_16x16x32_bf16(qa0, kb1, sc[0][1], 0, 0, 0);
    sc[1][0] = __builtin_amdgcn_mfma_f32_16x16x32_bf16(qa1, kb0, sc[1][0], 0, 0, 0);
    sc[1][1] = __builtin_amdgcn_mfma_f32_16x16x32_bf16(qa1, kb1, sc[1][1], 0, 0, 0);
  }

  // ---- softmax over 32 landmarks, 8 rows per lane (2 mi x 4 reg) ----
#pragma unroll
  for (int mi = 0; mi < 2; ++mi) {
#pragma unroll
    for (int i = 0; i < 4; ++i) {
      float s0 = sc[mi][0][i] * SCALE_F;
      float s1 = sc[mi][1][i] * SCALE_F;
      float mx = fmaxf(s0, s1);
#pragma unroll
      for (int off = 8; off; off >>= 1) mx = fmaxf(mx, __shfl_xor(mx, off));
      float p0 = __expf(s0 - mx), p1 = __expf(s1 - mx);
      float sum = p0 + p1;
#pragma unroll
      for (int off = 8; off; off >>= 1) sum += __shfl_xor(sum, off);
      float inv = 1.f / sum;
      int rr = mi * 16 + quad * 4 + i;               // 0..31 within wave tile
      P_s[w][rr][row16] = f2b(p0 * inv);
      P_s[w][rr][16 + row16] = f2b(p1 * inv);
    }
  }
  __syncthreads();

  // ---- PV: ctx[row][d] = sum_j P[row][j] V[j][d] ----
  bf8_t pa0 = *(const bf8_t*)&P_s[w][row16][quad * 8];
  bf8_t pa1 = *(const bf8_t*)&P_s[w][16 + row16][quad * 8];
  unsigned short* ctxb = CTX + (size_t)rowbase * DMODEL + h * HDIM;

#pragma unroll
  for (int dch = 0; dch < 12; ++dch) {
    bf8_t vb[4];
#pragma unroll
    for (int ni = 0; ni < 4; ++ni)
      vb[ni] = *(const bf8_t*)(VTb + (size_t)(dch * 64 + ni * 16 + row16) * 32 + quad * 8);
#pragma unroll
    for (int mi = 0; mi < 2; ++mi) {
      bf8_t pa = mi ? pa1 : pa0;
#pragma unroll
      for (int ni = 0; ni < 4; ++ni) {
        f4_t c = __builtin_amdgcn_mfma_f32_16x16x32_bf16(
            pa, vb[ni], (f4_t){0.f, 0.f, 0.f, 0.f}, 0, 0, 0);
#pragma unroll
        for (int i = 0; i < 4; ++i)
          ctxb[(size_t)(mi * 16 + quad * 4 + i) * DMODEL + dch * 64 + ni * 16 + row16] =
              f2b(c[i]);
      }
    }
  }
}

// ---------------- K4: landmark attention partials, JG=8, 64 k-chunks of 128 ----
// Wave owns (b,h,jg,kc): 8 landmarks x 128 K/V rows.  2048 waves = 512 blocks
// -> 2 blocks/CU, 2 waves/SIMD (launch_bounds caps VGPR at 256; needs ~232).
// K/V read once per 8 landmarks: 0.8 GB effective traffic.
__global__ __launch_bounds__(256, 2) void lm_attn_part(const unsigned short* __restrict__ QKV,
                                                       float* __restrict__ ctxpart,
                                                       float* __restrict__ mlpart) {
  int wid = blockIdx.x * 4 + (threadIdx.x >> 6);     // 0..2047
  int lane = threadIdx.x & 63;
  int kc = wid & 63, jg = (wid >> 6) & 3, h = (wid >> 8) & 3, b = wid >> 10;

  float qreg[8][12];
#pragma unroll
  for (int jj = 0; jj < 8; ++jj)
    load12(QKV + (size_t)(MTOK + b * NLM + jg * 8 + jj) * NQKV + h * HDIM + lane * 12,
           qreg[jj]);

  float m[8], l[8], ctx[8][12];
#pragma unroll
  for (int jj = 0; jj < 8; ++jj) {
    m[jj] = -1e30f;
    l[jj] = 0.f;
#pragma unroll
    for (int e = 0; e < 12; ++e) ctx[jj][e] = 0.f;
  }

  for (int k = kc * 128; k < kc * 128 + 128; ++k) {
    size_t row = (size_t)(b * S_LEN + k);
    float kv[12], vv[12];
    load12(QKV + row * NQKV + DMODEL + h * HDIM + lane * 12, kv);
    float s[8];
#pragma unroll
    for (int jj = 0; jj < 8; ++jj) {
      float p = 0.f;
#pragma unroll
      for (int e = 0; e < 12; ++e) p += qreg[jj][e] * kv[e];
      s[jj] = p;
    }
#pragma unroll
    for (int jj = 0; jj < 8; ++jj) {
#pragma unroll
      for (int off = 32; off; off >>= 1) s[jj] += __shfl_xor(s[jj], off);
      s[jj] *= SCALE_F;
    }
    load12(QKV + row * NQKV + 2 * DMODEL + h * HDIM + lane * 12, vv);
#pragma unroll
    for (int jj = 0; jj < 8; ++jj) {
      if (s[jj] <= m[jj]) {                          // wave-uniform branch
        float pp = __expf(s[jj] - m[jj]);
        l[jj] += pp;
#pragma unroll
        for (int e = 0; e < 12; ++e) ctx[jj][e] += pp * vv[e];
      } else {
        float al = __expf(m[jj] - s[jj]);
        m[jj] = s[jj];
        l[jj] = l[jj] * al + 1.f;
#pragma unroll
        for (int e = 0; e < 12; ++e) ctx[jj][e] = ctx[jj][e] * al + vv[e];
      }
    }
  }

#pragma unroll
  for (int jj = 0; jj < 8; ++jj) {
    int p = (((b * 4 + h) * 32) + (jg * 8 + jj)) * 64 + kc;
    float* cp = ctxpart + (size_t)p * HDIM + lane * 12;
#pragma unroll
    for (int e = 0; e < 12; ++e) cp[e] = ctx[jj][e];
    if (lane == 0) {
      mlpart[p * 2] = m[jj];
      mlpart[p * 2 + 1] = l[jj];
    }
  }
}

// ---------------- K4b: merge 64 landmark partials, wave per (b,h,j) ----------------
__global__ __launch_bounds__(256) void lm_combine(const float* __restrict__ ctxpart,
                                                  const float* __restrict__ mlpart,
                                                  unsigned short* __restrict__ CTX) {
  int wid = blockIdx.x * 4 + (threadIdx.x >> 6);     // 0..255
  int lane = threadIdx.x & 63;
  int j = wid & 31, h = (wid >> 5) & 3, b = wid >> 7;
  int base = wid * 64;
  float mk = mlpart[(base + lane) * 2];
  float lk = mlpart[(base + lane) * 2 + 1];
  float mm = mk;
#pragma unroll
  for (int off = 32; off; off >>= 1) mm = fmaxf(mm, __shfl_xor(mm, off));
  float al = __expf(mk - mm);
  float ls = al * lk;
#pragma unroll
  for (int off = 32; off; off >>= 1) ls += __shfl_xor(ls, off);

  float ctx[12];
#pragma unroll
  for (int e = 0; e < 12; ++e) ctx[e] = 0.f;
  for (int kc = 0; kc < 64; ++kc) {
    float a = __shfl(al, kc);
    const float* cp = ctxpart + (size_t)(base + kc) * HDIM + lane * 12;
#pragma unroll
    for (int e = 0; e < 12; ++e) ctx[e] += a * cp[e];
  }
  float inv = 1.f / ls;
#pragma unroll
  for (int e = 0; e < 12; ++e) ctx[e] *= inv;
  store12(CTX + (size_t)(MTOK + b * NLM + j) * DMODEL + h * HDIM + lane * 12, ctx);
}

// ---------------- K6: out = (landmark? lm_proj : hs) + global_proj ----------------
__global__ __launch_bounds__(256) void compose(const float* __restrict__ hs,
                                               const unsigned short* __restrict__ PROJ,
                                               float* __restrict__ out) {
  size_t idx = (size_t)blockIdx.x * 256 + threadIdx.x;
  size_t e = idx * 4;
  int row = (int)(e / DMODEL);
  int col = (int)(e - (size_t)row * DMODEL);
  int b = row >> 13, s = row & (S_LEN - 1);

  us4_t g4 = *(const us4_t*)(PROJ + (size_t)row * DMODEL + col);
  int j = -1;
  if ((s & 15) == 0) {
    int sel = s >> 4;
    int jc = (sel * 31 + 510) / 511;                 // ceil(sel*31/511): unique candidate
    if (jc < 32 && (jc * 511) / 31 == sel) j = jc;
  }
  f4_t base;
  if (j >= 0) {
    us4_t l4 = *(const us4_t*)(PROJ + (size_t)(MTOK + b * NLM + j) * DMODEL + col);
    base = (f4_t){b2f(l4[0]), b2f(l4[1]), b2f(l4[2]), b2f(l4[3])};
  } else {
    base = *(const f4_t*)(hs + e);
  }
  f4_t o = {base[0] + b2f(g4[0]), base[1] + b2f(g4[1]),
            base[2] + b2f(g4[2]), base[3] + b2f(g4[3])};
  *(f4_t*)(out + e) = o;
}

// ---------------- launch ----------------
extern "C" void kernel_launch(void* const* d_in, const int* in_sizes, int n_in,
                              void* d_out, int out_size, void* d_ws, size_t ws_size,
                              hipStream_t stream) {
  const float* hs   = (const float*)d_in[0];
  const float* lemb = (const float*)d_in[1];
  const float* Wq   = (const float*)d_in[2];
  const float* bq   = (const float*)d_in[3];
  const float* Wk   = (const float*)d_in[4];
  const float* bk   = (const float*)d_in[5];
  const float* Wv   = (const float*)d_in[6];
  const float* bv   = (const float*)d_in[7];
  const float* Wo   = (const float*)d_in[8];
  const float* bo   = (const float*)d_in[9];
  float* out = (float*)d_out;
  char* ws = (char*)d_ws;

  unsigned short* A    = (unsigned short*)(ws + OFF_A);
  unsigned short* Wt   = (unsigned short*)(ws + OFF_WT);
  unsigned short* QKV  = (unsigned short*)(ws + OFF_QKV);
  unsigned short* CTX  = (unsigned short*)(ws + OFF_CTX);
  float*          bcat = (float*)(ws + OFF_BCAT);
  unsigned short* KT   = (unsigned short*)(ws + OFF_KT);
  unsigned short* VT   = (unsigned short*)(ws + OFF_VT);
  float*          ml   = (float*)(ws + OFF_ML2);
  float*          cpart= (float*)(ws + OFF_CP);          // A region (dead window)
  unsigned short* PROJ = (unsigned short*)(ws + OFF_A);  // after lm_combine

  static bool attr_set = false;
  if (!attr_set) {
    (void)hipFuncSetAttribute(reinterpret_cast<const void*>(gemm256),
                              hipFuncAttributeMaxDynamicSharedMemorySize, 131072);
    attr_set = true;
  }

  build_bcat<<<dim3(48), dim3(256), 0, stream>>>(bq, bk, bv, bo, bcat);
  build_a<<<dim3(49536), dim3(256), 0, stream>>>(hs, lemb, A);
  wtrans<<<dim3(96, 96), dim3(32, 8), 0, stream>>>(Wq, Wt);
  wtrans<<<dim3(96, 96), dim3(32, 8), 0, stream>>>(Wk, Wt + (size_t)3072 * KDIM);
  wtrans<<<dim3(96, 96), dim3(32, 8), 0, stream>>>(Wv, Wt + (size_t)6144 * KDIM);
  wtrans<<<dim3(96, 96), dim3(32, 8), 0, stream>>>(Wo, Wt + (size_t)9216 * KDIM);

  // QKV for tokens + landmarks in one GEMM: [16448, 9216]; 65 x 36 tiles of 256
  gemm256<<<dim3(65 * 36), dim3(512), 131072, stream>>>(A, Wt, bcat, QKV, MV, NQKV, 36);

  kv_prep<<<dim3(192), dim3(256), 0, stream>>>(QKV, KT, VT);
  glob_attn<<<dim3(512), dim3(256), 0, stream>>>(QKV, KT, VT, CTX);
  lm_attn_part<<<dim3(512), dim3(256), 0, stream>>>(QKV, cpart, ml);
  lm_combine<<<dim3(64), dim3(256), 0, stream>>>(cpart, ml, CTX);

  // output projection for both ctx sets: [16448, 3072]; 65 x 12 tiles of 256
  gemm256<<<dim3(65 * 12), dim3(512), 131072, stream>>>(
      CTX, Wt + (size_t)9216 * KDIM, bcat + 9216, PROJ, MV, DMODEL, 12);

  compose<<<dim3(49152), dim3(256), 0, stream>>>(hs, PROJ, out);
}